// Round 6
// baseline (699.426 us; speedup 1.0000x reference)
//
#include <hip/hip_runtime.h>
#include <stdint.h>

// LSTMNet: B=2048, T=512, IN=64, H=64, 4H=256, 2 layers, FC to 4 classes.
// R8b: identical to R8 (round 4 was an infra failure — container died before
// any verdict; audit found no hang risk: uniform barriers, standard
// lgkmcnt+barrier pattern, bounded VGPR). R5 geometry (512 WGs x 512 thr,
// NB=4, 2 blocks/CU, 16 waves/CU = 4/SIMD for TLP) + R6/R7 lessons:
//  - fp16 everywhere (no hi/lo split, no bpermute fold): lane kg owns batch
//    kg (row 4kg -> acc reg 0). Lean waves: 16 MFMA + ~1 cell chain each.
//  - LIGHT BARRIER: s_waitcnt lgkmcnt(0) + s_barrier (no vmcnt drain!) so
//    the in-flight HBM x prefetch never lands on the barrier.
//  - x 2-deep register prefetch by L1 waves; consumed ~1 full iter later.
//  - s_setprio(1) around MFMA cluster (16 waves, 2 drifting blocks).
// Model (calibrated R5/R6/R7): iter = MFMA-pipe (64 MFMA/SIMD x 19.4cy =
// 1242) + exposed-serial (~970 @2blk). This round targets the serial term.

#define T_SEQ  512
#define NB     4
#define PSTR   136          // panel0 row stride (shorts): 272B, 16B-aligned
#define PANEL  (16 * PSTR)
#define PSTR2  72           // panel1 row stride (shorts): 144B, 16B-aligned
#define PANEL2 (16 * PSTR2)

typedef __attribute__((ext_vector_type(8))) _Float16 half8;   // 8 x f16
typedef __attribute__((ext_vector_type(4))) float    float4v; // MFMA C/D

#define LBAR() asm volatile("s_waitcnt lgkmcnt(0)\n\ts_barrier" ::: "memory")

__device__ __forceinline__ float sigm(float x) {
    return __builtin_amdgcn_rcpf(1.0f + __builtin_amdgcn_exp2f(-1.44269504088896f * x));
}
__device__ __forceinline__ float tanh_f(float x) {
    float e = __builtin_amdgcn_exp2f(-2.88539008177793f * x);   // exp(-2x)
    return __builtin_fmaf(2.0f, __builtin_amdgcn_rcpf(1.0f + e), -1.0f);
}

__global__ __launch_bounds__(512, 4) void lstm2_kernel(
    const float* __restrict__ x,
    const float* __restrict__ wih0, const float* __restrict__ whh0,
    const float* __restrict__ bih0, const float* __restrict__ bhh0,
    const float* __restrict__ wih1, const float* __restrict__ whh1,
    const float* __restrict__ bih1, const float* __restrict__ bhh1,
    const float* __restrict__ fcw,  const float* __restrict__ fcb,
    float* __restrict__ out)
{
    // panel0: cols [0,64)=x_t, [64,128)=h_l0.  panel1: cols [0,64)=h_l1.
    // Rows: batch b at row 4b; rows 4b+1..3 stay zero (C rows land in acc
    // regs 1..3 which are ignored).
    __shared__ __align__(16) unsigned short panel0[2][PANEL];
    __shared__ __align__(16) unsigned short panel1[2][PANEL2];
    __shared__ float h2buf[NB * 64];
    __shared__ float fcw_s[256];
    __shared__ float fcb_s[4];

    const int tid  = threadIdx.x;
    const int lane = tid & 63;
    const int wave = tid >> 6;
    const int mrow = lane & 15;         // A m-row base / B n-within-tile / C col
    const int kg   = lane >> 4;         // k-quad / C row-group / lane's batch
    const int lset = wave >> 2;         // 0 = layer-0 waves, 1 = layer-1 waves
    const int ws   = wave & 3;          // h-slice [16*ws, 16*ws+16)
    const int b0   = blockIdx.x * NB;

    for (int i = tid; i < 256; i += 512) fcw_s[i] = fcw[i];
    if (tid < 4) fcb_s[tid] = fcb[tid];
    for (int i = tid; i < 2 * PANEL; i += 512)  panel0[0][i] = 0;
    for (int i = tid; i < 2 * PANEL2; i += 512) panel1[0][i] = 0;

    const float* wih  = lset ? wih1 : wih0;
    const float* whh  = lset ? whh1 : whh0;
    const float* bihp = lset ? bih1 : bih0;
    const float* bhhp = lset ? bhh1 : bhh0;

    const int hcol = ws * 16 + mrow;

    // Per-lane gate biases: gate g at n = g*64 + hcol.
    float biasg[4];
    #pragma unroll
    for (int g = 0; g < 4; ++g) {
        const int idx = g * 64 + hcol;
        biasg[g] = bihp[idx] + bhhp[idx];
    }

    // Weight B-frags (fp16): wave owns n-tiles {ws,4+ws,8+ws,12+ws} = gates
    // i,f,g,o of its slice. n = tile*16 + mrow, k = kt*32 + kg*8 + j.
    // Combined K=128: k<64 -> w_ih[n][k]; k>=64 -> w_hh[n][k-64].
    half8 wf[4][4];                     // 64 VGPRs
    #pragma unroll
    for (int g = 0; g < 4; ++g) {
        const int n = (g * 4 + ws) * 16 + mrow;
        #pragma unroll
        for (int kt = 0; kt < 4; ++kt) {
            const int k0 = kt * 32 + kg * 8;
            const float* src = (k0 < 64) ? (wih + n * 64 + k0)
                                         : (whh + n * 64 + (k0 - 64));
            half8 hv8;
            #pragma unroll
            for (int j = 0; j < 8; ++j) hv8[j] = (_Float16)src[j];
            wf[g][kt] = hv8;
        }
    }

    __syncthreads();                    // panels zeroed (full barrier, cold)
    // Stage x(0): L1 waves, batch ws, col lane, row 4*ws.
    const int sxof = 4 * ws * PSTR + lane;
    if (lset == 1) {
        float xv = x[((size_t)(b0 + ws) * T_SEQ + 0) * 64 + lane];
        panel0[0][sxof] = __builtin_bit_cast(unsigned short, (_Float16)xv);
    }
    __syncthreads();

    // Per-lane constant addressing (shorts).
    const int fragoff0 = mrow * PSTR  + kg * 8;
    const int fragoff1 = mrow * PSTR2 + kg * 8;
    // L0: A = {x k0..63 , h0 k0..63} both in panel0 (cols 0..127).
    // L1: A = {h0 k0..63 (panel0 cols 64+), h1 k0..63 (panel1)}.
    const unsigned short* rdA = &panel0[0][0] + fragoff0 + (lset ? 64 : 0);
    const unsigned short* rdB = lset ? (&panel1[0][0] + fragoff1)
                                     : (&panel0[0][0] + fragoff0 + 64);
    const int h0off = 4 * kg * PSTR  + 64 + hcol;   // h0 write (panel0)
    const int h1off = 4 * kg * PSTR2 + hcol;        // h1 write (panel1)

    // x stream (L1 waves), 2 steps ahead: xcur holds x(s+1) at iter s.
    float xcur = 0.f;
    const float* xp = x + ((size_t)(b0 + ws) * T_SEQ + 2) * 64 + lane;
    if (lset == 1) xcur = x[((size_t)(b0 + ws) * T_SEQ + 1) * 64 + lane];

    float c = 0.f;
    const float4v z4 = {0.f, 0.f, 0.f, 0.f};

    for (int s = 0; s <= T_SEQ; ++s) {
        const int p     = s & 1;
        const int poff  = p * PANEL;
        const int poff2 = p * PANEL2;
        const int qoff  = poff  ^ PANEL;
        const int qoff2 = poff2 ^ PANEL2;

        // Issue x(s+2) load (L1 waves; wave-uniform condition). The light
        // barrier never drains vmcnt, so this flies across iterations.
        const bool ld = (lset == 1) && ((s + 2) < T_SEQ);
        float xnext = 0.f;
        if (ld) xnext = *xp;

        // ---- A-frags: 4 x ds_read_b128 ----
        const unsigned short* pA = rdA + poff;
        const unsigned short* pB = rdB + (lset ? poff2 : poff);
        half8 af0 = *(const half8*)(pA);
        half8 af1 = *(const half8*)(pA + 32);
        half8 af2 = *(const half8*)(pB);
        half8 af3 = *(const half8*)(pB + 32);

        // ---- MFMA: 4 gate chains, depth 4 ----
        __builtin_amdgcn_s_setprio(1);
        float4v acc[4];
        #pragma unroll
        for (int g = 0; g < 4; ++g)
            acc[g] = __builtin_amdgcn_mfma_f32_16x16x32_f16(af0, wf[g][0], z4, 0, 0, 0);
        #pragma unroll
        for (int g = 0; g < 4; ++g)
            acc[g] = __builtin_amdgcn_mfma_f32_16x16x32_f16(af1, wf[g][1], acc[g], 0, 0, 0);
        #pragma unroll
        for (int g = 0; g < 4; ++g)
            acc[g] = __builtin_amdgcn_mfma_f32_16x16x32_f16(af2, wf[g][2], acc[g], 0, 0, 0);
        #pragma unroll
        for (int g = 0; g < 4; ++g)
            acc[g] = __builtin_amdgcn_mfma_f32_16x16x32_f16(af3, wf[g][3], acc[g], 0, 0, 0);
        __builtin_amdgcn_s_setprio(0);

        // ---- Cell (writes go to the OTHER buffer; 1 light barrier/iter) ----
        const bool active = lset ? (s > 0) : (s < T_SEQ);
        if (active) {                   // wave-uniform
            float g0 = acc[0][0] + biasg[0];
            float g1 = acc[1][0] + biasg[1];
            float g2 = acc[2][0] + biasg[2];
            float g3 = acc[3][0] + biasg[3];
            float ig = sigm(g0), fg = sigm(g1);
            float gt = tanh_f(g2), og = sigm(g3);
            c = fg * c + ig * gt;
            float hv = og * tanh_f(c);
            unsigned short hbits = __builtin_bit_cast(unsigned short, (_Float16)hv);
            if (lset == 0) {
                panel0[0][qoff + h0off] = hbits;
            } else {
                panel1[0][qoff2 + h1off] = hbits;
                if (s == T_SEQ) h2buf[(kg << 6) + hcol] = hv;
            }
        }
        if (lset == 1 && (s + 1) < T_SEQ) {   // stage x(s+1) from reg
            panel0[0][qoff + sxof] = __builtin_bit_cast(unsigned short, (_Float16)xcur);
        }
        xcur = xnext;
        if (ld) xp += 64;
        LBAR();
    }

    // ---- FC head ----
    if (tid < 16) {
        const int bb = tid >> 2, nc = tid & 3;
        float s = fcb_s[nc];
        #pragma unroll 8
        for (int h = 0; h < 64; ++h) s += h2buf[bb * 64 + h] * fcw_s[nc * 64 + h];
        out[(size_t)(b0 + bb) * 4 + nc] = s;
    }
}

extern "C" void kernel_launch(void* const* d_in, const int* in_sizes, int n_in,
                              void* d_out, int out_size, void* d_ws, size_t ws_size,
                              hipStream_t stream) {
    const float* x    = (const float*)d_in[0];
    const float* wih0 = (const float*)d_in[1];
    const float* whh0 = (const float*)d_in[2];
    const float* bih0 = (const float*)d_in[3];
    const float* bhh0 = (const float*)d_in[4];
    const float* wih1 = (const float*)d_in[5];
    const float* whh1 = (const float*)d_in[6];
    const float* bih1 = (const float*)d_in[7];
    const float* bhh1 = (const float*)d_in[8];
    const float* fcw  = (const float*)d_in[9];
    const float* fcb  = (const float*)d_in[10];
    float* out = (float*)d_out;
    (void)d_ws; (void)ws_size; (void)in_sizes; (void)n_in; (void)out_size;

    lstm2_kernel<<<dim3(2048 / NB), dim3(512), 0, stream>>>(
        x, wih0, whh0, bih0, bhh0, wih1, whh1, bih1, bhh1, fcw, fcb, out);
}